// Round 1
// baseline (400.699 us; speedup 1.0000x reference)
//
#include <hip/hip_runtime.h>
#include <math.h>

// GCNII graph convolution, N=50000 nodes, F=256 feats, E=800000 edges, all f32.
// Plan: device-side CSR build (count -> scan -> fill), pull-based gather
// (1 wave per row, coalesced float4 H-row reads, register accumulation),
// then bf16-MFMA GEMM for init_res @ W with f32 epilogue mix.

#define F_DIM 256

typedef __attribute__((ext_vector_type(4))) float f32x4;
typedef __attribute__((ext_vector_type(8))) short short8;

static __device__ __forceinline__ unsigned short f2bf(float f) {
    // round-to-nearest-even f32 -> bf16 (finite inputs)
    unsigned int u = __float_as_uint(f);
    u += 0x7fffu + ((u >> 16) & 1u);
    return (unsigned short)(u >> 16);
}

// ---- CSR build ------------------------------------------------------------

__global__ void count_kernel(const int* __restrict__ src, const int* __restrict__ dst,
                             int* cnt_src, int* cnt_dst, int E) {
    int e = blockIdx.x * blockDim.x + threadIdx.x;
    if (e < E) {
        atomicAdd(&cnt_src[src[e]], 1);
        atomicAdd(&cnt_dst[dst[e]], 1);
    }
}

// single-block exclusive scan over n counts -> row_ptr[0..n]
__global__ void scan_kernel(const int* __restrict__ cnt, int* __restrict__ row_ptr, int n) {
    __shared__ int sm[1024];
    int tid = threadIdx.x;
    int carry = 0;
    for (int base = 0; base < n; base += 1024) {
        int i = base + tid;
        int v = (i < n) ? cnt[i] : 0;
        sm[tid] = v;
        __syncthreads();
        for (int off = 1; off < 1024; off <<= 1) {
            int t = (tid >= off) ? sm[tid - off] : 0;
            __syncthreads();
            sm[tid] += t;
            __syncthreads();
        }
        if (i < n) row_ptr[i] = carry + sm[tid] - v;   // exclusive
        carry += sm[1023];
        __syncthreads();
    }
    if (tid == 0) row_ptr[n] = carry;
}

__global__ void dinv_kernel(const int* __restrict__ cnt_dst,
                            float* __restrict__ dinv, float* __restrict__ dginv, int n) {
    int i = blockIdx.x * blockDim.x + threadIdx.x;
    if (i < n) {
        float deg = (float)cnt_dst[i] + 1.0f;   // A_hat column sum (+ self loop)
        dinv[i]  = rsqrtf(deg);
        dginv[i] = 1.0f / deg;
    }
}

__global__ void fill_kernel(const int* __restrict__ src, const int* __restrict__ dst,
                            const int* __restrict__ row_ptr, int* cursor,
                            int* __restrict__ col, int E) {
    int e = blockIdx.x * blockDim.x + threadIdx.x;
    if (e < E) {
        int s = src[e];
        int pos = atomicAdd(&cursor[s], 1);
        col[row_ptr[s] + pos] = dst[e];
    }
}

// ---- W transpose to bf16 (Wt[n][k] = bf16(W[k][n])) -----------------------

__global__ void wt_kernel(const float* __restrict__ W, unsigned short* __restrict__ Wt) {
    int n = blockIdx.x;
    int k = threadIdx.x;
    Wt[n * F_DIM + k] = f2bf(W[k * F_DIM + n]);
}

// ---- gather: one wave per row, lane owns 4 consecutive feats (float4) -----

__global__ __launch_bounds__(256) void gather_kernel(
        const float* __restrict__ H, const float* __restrict__ H0,
        const int* __restrict__ row_ptr, const int* __restrict__ col,
        const float* __restrict__ dinv, const float* __restrict__ dginv,
        const float* __restrict__ alpha_p, float* __restrict__ ir, int n) {
    int wave = threadIdx.x >> 6;
    int lane = threadIdx.x & 63;
    int row = blockIdx.x * 4 + wave;
    if (row >= n) return;
    float alpha = alpha_p[0];
    const f32x4* H4 = (const f32x4*)H;
    const f32x4* H04 = (const f32x4*)H0;

    f32x4 acc = 0.0f;
    int beg = row_ptr[row], end = row_ptr[row + 1];
    for (int e = beg; e < end; ++e) {
        int j = col[e];
        float dj = dinv[j];
        f32x4 h = H4[j * 64 + lane];   // 64 lanes x 16B = 1KB coalesced
        acc += h * dj;
    }
    float di = dinv[row], dgi = dginv[row];
    f32x4 h  = H4[row * 64 + lane];
    f32x4 h0 = H04[row * 64 + lane];
    f32x4 ph = di * acc + h * dgi;
    f32x4 init = (1.0f - alpha) * ph + alpha * h0;
    ((f32x4*)ir)[row * 64 + lane] = init;
}

// ---- GEMM: out = (1-beta)*ir + beta*(ir @ W), bf16 MFMA 16x16x32 ----------
// 1 wave per block; wave tile = 64 rows x 64 cols; K = 256 in 8 steps.

__global__ __launch_bounds__(64) void gemm_kernel(
        const float* __restrict__ ir, const unsigned short* __restrict__ Wt,
        float* __restrict__ out, const float* __restrict__ lamda_p,
        const int* __restrict__ l_p, int M) {
    int wid = blockIdx.x;
    int mr = (wid >> 2) * 64;
    int nc = (wid & 3) * 64;
    int lane = threadIdx.x;
    int lo = lane & 15, hi = lane >> 4;
    float beta = logf(lamda_p[0] / (float)l_p[0] + 1.0f);
    float ob = 1.0f - beta;

    f32x4 acc[4][4] = {};
    for (int kk = 0; kk < 8; ++kk) {
        int kb = kk * 32 + hi * 8;
        short8 a[4], b[4];
        for (int am = 0; am < 4; ++am) {
            int row = mr + am * 16 + lo;
            if (row < M) {
                const float* p = ir + (size_t)row * F_DIM + kb;
                f32x4 x0 = *(const f32x4*)p;
                f32x4 x1 = *(const f32x4*)(p + 4);
                short8 t;
                t[0] = (short)f2bf(x0[0]); t[1] = (short)f2bf(x0[1]);
                t[2] = (short)f2bf(x0[2]); t[3] = (short)f2bf(x0[3]);
                t[4] = (short)f2bf(x1[0]); t[5] = (short)f2bf(x1[1]);
                t[6] = (short)f2bf(x1[2]); t[7] = (short)f2bf(x1[3]);
                a[am] = t;
            } else {
                a[am] = (short8)0;
            }
        }
        for (int bn = 0; bn < 4; ++bn) {
            int cb = nc + bn * 16 + lo;
            b[bn] = *(const short8*)(Wt + cb * F_DIM + kb);   // contiguous 16B
        }
        for (int am = 0; am < 4; ++am)
            for (int bn = 0; bn < 4; ++bn)
                acc[am][bn] = __builtin_amdgcn_mfma_f32_16x16x32_bf16(
                    a[am], b[bn], acc[am][bn], 0, 0, 0);
    }

    // C/D layout: col = lane&15, row = (lane>>4)*4 + reg   [m89-verified]
    for (int am = 0; am < 4; ++am) {
        int rbase = mr + am * 16 + hi * 4;
        for (int r = 0; r < 4; ++r) {
            int row = rbase + r;
            if (row >= M) continue;
            for (int bn = 0; bn < 4; ++bn) {
                int c2 = nc + bn * 16 + lo;
                size_t idx = (size_t)row * F_DIM + c2;
                out[idx] = ob * ir[idx] + beta * acc[am][bn][r];
            }
        }
    }
}

// ---- launch ---------------------------------------------------------------

extern "C" void kernel_launch(void* const* d_in, const int* in_sizes, int n_in,
                              void* d_out, int out_size, void* d_ws, size_t ws_size,
                              hipStream_t stream) {
    const float* H     = (const float*)d_in[0];
    const int*   ei    = (const int*)d_in[1];
    const float* H0    = (const float*)d_in[2];
    const float* W     = (const float*)d_in[3];
    const float* lamda = (const float*)d_in[4];
    const float* alpha = (const float*)d_in[5];
    const int*   lp    = (const int*)d_in[6];

    int n = in_sizes[0] / F_DIM;
    int E = in_sizes[1] / 2;
    const int* src = ei;
    const int* dst = ei + E;
    float* out = (float*)d_out;

    char* ws = (char*)d_ws;
    size_t off = 0;
    auto alloc = [&](size_t bytes) -> void* {
        void* p = ws + off;
        off += (bytes + 255) & ~(size_t)255;
        return p;
    };
    int* cnt_src = (int*)alloc((size_t)n * 4);
    int* cnt_dst = (int*)alloc((size_t)n * 4);
    int* cursor  = (int*)alloc((size_t)n * 4);
    int* row_ptr = (int*)alloc(((size_t)n + 1) * 4);
    float* dinv  = (float*)alloc((size_t)n * 4);
    float* dginv = (float*)alloc((size_t)n * 4);
    int* colb    = (int*)alloc((size_t)E * 4);
    unsigned short* Wt = (unsigned short*)alloc((size_t)F_DIM * F_DIM * 2);
    float* ir    = (float*)alloc((size_t)n * F_DIM * 4);

    // zero the three count/cursor arrays (contiguous region up to row_ptr)
    hipMemsetAsync(cnt_src, 0, (char*)row_ptr - (char*)cnt_src, stream);

    count_kernel<<<(E + 255) / 256, 256, 0, stream>>>(src, dst, cnt_src, cnt_dst, E);
    scan_kernel<<<1, 1024, 0, stream>>>(cnt_src, row_ptr, n);
    dinv_kernel<<<(n + 255) / 256, 256, 0, stream>>>(cnt_dst, dinv, dginv, n);
    fill_kernel<<<(E + 255) / 256, 256, 0, stream>>>(src, dst, row_ptr, cursor, colb, E);
    wt_kernel<<<F_DIM, F_DIM, 0, stream>>>(W, Wt);
    gather_kernel<<<(n + 3) / 4, 256, 0, stream>>>(H, H0, row_ptr, colb, dinv, dginv,
                                                   alpha, ir, n);
    int mtiles = (n + 63) / 64;
    gemm_kernel<<<mtiles * 4, 64, 0, stream>>>(ir, Wt, out, lamda, lp, n);
}

// Round 2
// 343.710 us; speedup vs baseline: 1.1658x; 1.1658x over previous
//
#include <hip/hip_runtime.h>
#include <math.h>

// GCNII graph convolution, N=50000, F=256, E=800000, f32 in/out.
// R2: bf16 gather payload (Hs = bf16(H*dinv), 512B/row instead of 1KB),
//     shfl-based single-block scan (was ~100us ladder scan),
//     bf16 ir -> GEMM A-frags are direct short8 loads.

#define F_DIM 256

typedef __attribute__((ext_vector_type(4))) float f32x4;
typedef __attribute__((ext_vector_type(8))) short short8;
typedef __attribute__((ext_vector_type(4))) unsigned short u16x4;

static __device__ __forceinline__ unsigned short f2bf(float f) {
    unsigned int u = __float_as_uint(f);
    u += 0x7fffu + ((u >> 16) & 1u);
    return (unsigned short)(u >> 16);
}
static __device__ __forceinline__ float bf2f(unsigned short u) {
    return __uint_as_float((unsigned int)u << 16);
}

// ---- CSR build ------------------------------------------------------------

__global__ void count_kernel(const int* __restrict__ src, const int* __restrict__ dst,
                             int* cnt_src, int* cnt_dst, int E) {
    int e = blockIdx.x * blockDim.x + threadIdx.x;
    if (e < E) {
        atomicAdd(&cnt_src[src[e]], 1);
        atomicAdd(&cnt_dst[dst[e]], 1);
    }
}

// single-block scan: thread owns a contiguous chunk; wave shfl-scan of sums.
__global__ __launch_bounds__(1024) void scan_kernel(const int* __restrict__ cnt,
                                                    int* __restrict__ row_ptr, int n) {
    __shared__ int wsum[16];
    int tid = threadIdx.x;
    int C = (n + 1023) / 1024;
    int beg = tid * C;
    int end = beg + C < n ? beg + C : n;
    int s = 0;
    for (int i = beg; i < end; ++i) s += cnt[i];
    int lane = tid & 63, wid = tid >> 6;
    int v = s;
    for (int off = 1; off < 64; off <<= 1) {
        int t = __shfl_up(v, off, 64);
        if (lane >= off) v += t;
    }
    if (lane == 63) wsum[wid] = v;
    __syncthreads();
    if (tid == 0) {
        int run = 0;
        for (int w = 0; w < 16; ++w) { int t = wsum[w]; wsum[w] = run; run += t; }
    }
    __syncthreads();
    int run = wsum[wid] + v - s;          // exclusive prefix for this chunk
    for (int i = beg; i < end; ++i) { row_ptr[i] = run; run += cnt[i]; }
    if (tid == 1023) row_ptr[n] = run;    // last chunks are empty => run == total
}

__global__ void dinv_kernel(const int* __restrict__ cnt_dst,
                            float* __restrict__ dinv, int n) {
    int i = blockIdx.x * blockDim.x + threadIdx.x;
    if (i < n) dinv[i] = rsqrtf((float)cnt_dst[i] + 1.0f);
}

__global__ void fill_kernel(const int* __restrict__ src, const int* __restrict__ dst,
                            const int* __restrict__ row_ptr, int* cursor,
                            int* __restrict__ col, int E) {
    int e = blockIdx.x * blockDim.x + threadIdx.x;
    if (e < E) {
        int s = src[e];
        int pos = atomicAdd(&cursor[s], 1);
        col[row_ptr[s] + pos] = dst[e];
    }
}

// ---- Hs = bf16(H * dinv[row]) ---------------------------------------------

__global__ __launch_bounds__(256) void hs_kernel(const float* __restrict__ H,
                                                 const float* __restrict__ dinv,
                                                 unsigned short* __restrict__ Hs,
                                                 int total4) {
    int i = blockIdx.x * 256 + threadIdx.x;   // index in f32x4 / u16x4 units
    if (i >= total4) return;
    int row = i >> 6;                          // 64 x f32x4 per row
    float d = dinv[row];
    f32x4 x = ((const f32x4*)H)[i];
    u16x4 o;
    o[0] = f2bf(x[0] * d); o[1] = f2bf(x[1] * d);
    o[2] = f2bf(x[2] * d); o[3] = f2bf(x[3] * d);
    ((u16x4*)Hs)[i] = o;
}

// ---- W transpose to bf16 (Wt[n][k]) ---------------------------------------

__global__ void wt_kernel(const float* __restrict__ W, unsigned short* __restrict__ Wt) {
    int n = blockIdx.x;
    int k = threadIdx.x;
    Wt[n * F_DIM + k] = f2bf(W[k * F_DIM + n]);
}

// ---- gather: one wave per row; lane owns 4 feats; bf16 payload ------------

__global__ __launch_bounds__(256) void gather_kernel(
        const unsigned short* __restrict__ Hs, const float* __restrict__ H0,
        const int* __restrict__ row_ptr, const int* __restrict__ col,
        const float* __restrict__ dinv, const float* __restrict__ alpha_p,
        unsigned short* __restrict__ irb, int n) {
    int wave = threadIdx.x >> 6;
    int lane = threadIdx.x & 63;
    int row = blockIdx.x * 4 + wave;
    if (row >= n) return;
    float alpha = alpha_p[0];
    const u16x4* Hs4 = (const u16x4*)Hs;

    f32x4 acc = 0.0f;
    int beg = row_ptr[row], end = row_ptr[row + 1];
    for (int e = beg; e < end; ++e) {
        int j = col[e];
        u16x4 h = Hs4[j * 64 + lane];          // 64 lanes x 8B = 512B coalesced
        acc[0] += bf2f(h[0]); acc[1] += bf2f(h[1]);
        acc[2] += bf2f(h[2]); acc[3] += bf2f(h[3]);
    }
    // self loop: H/deg = Hs * dinv  =>  PH = dinv[row] * (acc + Hs_row)
    u16x4 hr = Hs4[row * 64 + lane];
    acc[0] += bf2f(hr[0]); acc[1] += bf2f(hr[1]);
    acc[2] += bf2f(hr[2]); acc[3] += bf2f(hr[3]);
    float di = dinv[row];
    f32x4 h0 = ((const f32x4*)H0)[row * 64 + lane];
    f32x4 init = (1.0f - alpha) * (di * acc) + alpha * h0;
    u16x4 o;
    o[0] = f2bf(init[0]); o[1] = f2bf(init[1]);
    o[2] = f2bf(init[2]); o[3] = f2bf(init[3]);
    ((u16x4*)irb)[row * 64 + lane] = o;
}

// ---- GEMM: out = (1-beta)*irb + beta*(irb @ W), bf16 MFMA 16x16x32 --------
// 1 wave per block; wave tile = 64 rows x 64 cols; K = 256 in 8 steps.

__global__ __launch_bounds__(64) void gemm_kernel(
        const unsigned short* __restrict__ irb, const unsigned short* __restrict__ Wt,
        float* __restrict__ out, const float* __restrict__ lamda_p,
        const int* __restrict__ l_p, int M) {
    int wid = blockIdx.x;
    int mr = (wid >> 2) * 64;
    int nc = (wid & 3) * 64;
    int lane = threadIdx.x;
    int lo = lane & 15, hi = lane >> 4;
    float beta = logf(lamda_p[0] / (float)l_p[0] + 1.0f);
    float ob = 1.0f - beta;

    f32x4 acc[4][4] = {};
    for (int kk = 0; kk < 8; ++kk) {
        int kb = kk * 32 + hi * 8;
        short8 a[4], b[4];
        for (int am = 0; am < 4; ++am) {
            int row = mr + am * 16 + lo;
            a[am] = (row < M) ? *(const short8*)(irb + (size_t)row * F_DIM + kb)
                              : (short8)0;
        }
        for (int bn = 0; bn < 4; ++bn) {
            int cb = nc + bn * 16 + lo;
            b[bn] = *(const short8*)(Wt + cb * F_DIM + kb);
        }
        for (int am = 0; am < 4; ++am)
            for (int bn = 0; bn < 4; ++bn)
                acc[am][bn] = __builtin_amdgcn_mfma_f32_16x16x32_bf16(
                    a[am], b[bn], acc[am][bn], 0, 0, 0);
    }

    // C/D layout: col = lane&15, row = (lane>>4)*4 + reg   [m89-verified]
    for (int am = 0; am < 4; ++am) {
        int rbase = mr + am * 16 + hi * 4;
        for (int r = 0; r < 4; ++r) {
            int row = rbase + r;
            if (row >= M) continue;
            for (int bn = 0; bn < 4; ++bn) {
                int c2 = nc + bn * 16 + lo;
                size_t idx = (size_t)row * F_DIM + c2;
                out[idx] = ob * bf2f(irb[idx]) + beta * acc[am][bn][r];
            }
        }
    }
}

// ---- launch ---------------------------------------------------------------

extern "C" void kernel_launch(void* const* d_in, const int* in_sizes, int n_in,
                              void* d_out, int out_size, void* d_ws, size_t ws_size,
                              hipStream_t stream) {
    const float* H     = (const float*)d_in[0];
    const int*   ei    = (const int*)d_in[1];
    const float* H0    = (const float*)d_in[2];
    const float* W     = (const float*)d_in[3];
    const float* lamda = (const float*)d_in[4];
    const float* alpha = (const float*)d_in[5];
    const int*   lp    = (const int*)d_in[6];

    int n = in_sizes[0] / F_DIM;
    int E = in_sizes[1] / 2;
    const int* src = ei;
    const int* dst = ei + E;
    float* out = (float*)d_out;

    char* ws = (char*)d_ws;
    size_t off = 0;
    auto alloc = [&](size_t bytes) -> void* {
        void* p = ws + off;
        off += (bytes + 255) & ~(size_t)255;
        return p;
    };
    int* cnt_src = (int*)alloc((size_t)n * 4);
    int* cnt_dst = (int*)alloc((size_t)n * 4);
    int* cursor  = (int*)alloc((size_t)n * 4);
    int* row_ptr = (int*)alloc(((size_t)n + 1) * 4);
    float* dinv  = (float*)alloc((size_t)n * 4);
    int* colb    = (int*)alloc((size_t)E * 4);
    unsigned short* Wt  = (unsigned short*)alloc((size_t)F_DIM * F_DIM * 2);
    unsigned short* Hs  = (unsigned short*)alloc((size_t)n * F_DIM * 2);
    unsigned short* irb = (unsigned short*)alloc(((size_t)n + 64) * F_DIM * 2); // +64 rows: gemm tail reads

    // zero count/cursor arrays (contiguous region up to row_ptr)
    hipMemsetAsync(cnt_src, 0, (char*)row_ptr - (char*)cnt_src, stream);

    count_kernel<<<(E + 255) / 256, 256, 0, stream>>>(src, dst, cnt_src, cnt_dst, E);
    scan_kernel<<<1, 1024, 0, stream>>>(cnt_src, row_ptr, n);
    dinv_kernel<<<(n + 255) / 256, 256, 0, stream>>>(cnt_dst, dinv, n);
    fill_kernel<<<(E + 255) / 256, 256, 0, stream>>>(src, dst, row_ptr, cursor, colb, E);
    hs_kernel<<<(n * 64 + 255) / 256, 256, 0, stream>>>(H, dinv, Hs, n * 64);
    wt_kernel<<<F_DIM, F_DIM, 0, stream>>>(W, Wt);
    gather_kernel<<<(n + 3) / 4, 256, 0, stream>>>(Hs, H0, row_ptr, colb, dinv,
                                                   alpha, irb, n);
    int mtiles = (n + 63) / 64;
    gemm_kernel<<<mtiles * 4, 64, 0, stream>>>(irb, Wt, out, lamda, lp, n);
}